// Round 17
// baseline (229.281 us; speedup 1.0000x reference)
//
#include <hip/hip_runtime.h>
#include <hip/hip_bf16.h>
#include <hip/hip_fp16.h>

#define N_NODES  50000
#define N_EDGES  800000
#define D        128
#define N_GRAPHS 64
#define CAP      64          // bucket capacity; in-deg ~ Poisson(16), P(>=64) ~ 1e-19
#define EW_SCALE 1048576.0f  // 2^20 fixed-point for packed weighted-degree
#define NB_G1M   782         // ceil(50000/64) MFMA gemm1 blocks
#define NB_FILL  3125        // 800000/256
#define NB_AGG16 3125        // N_NODES/16

typedef _Float16 half8 __attribute__((ext_vector_type(8)));
typedef float   float4v __attribute__((ext_vector_type(4)));

__device__ __forceinline__ float2 h2f(unsigned int u) {
    __half2 h = *reinterpret_cast<__half2*>(&u);
    return __half22float2(h);
}
__device__ __forceinline__ float hu2f(unsigned short u) {
    __half_raw hr; hr.x = u;
    return __half2float(__half(hr));
}
// unpack packed word -> (cnt, dinv)
__device__ __forceinline__ void unpack_pd(unsigned long long p, int& n, float& dv) {
    int c = (int)(p >> 40);
    n = c < CAP ? c : CAP;
    dv = rsqrtf(1.0f + (float)(p & 0xFFFFFFFFFFULL) * (1.0f / EW_SCALE));
}

// ---------------------------------------------------------------------------
// FUSED, LDS-FREE: blocks [0,782) = MFMA gemm1 (fp32 x -> in-reg fp16 @ W1,
// one wave per 16-row strip, B strided from L2-hot W1); blocks [782,3907) =
// fill (1 edge/thread, returning 64-bit atomic on 50K spread counters).
// No __shared__ at all -> fill blocks occupancy is VGPR-limited only.
// ---------------------------------------------------------------------------
__global__ __launch_bounds__(256) void fused_gemm1_fill(const float* __restrict__ X,
                                                        const float* __restrict__ W,
                                                        __half* __restrict__ Yh,
                                                        const int* __restrict__ ei,
                                                        const float* __restrict__ ew,
                                                        unsigned long long* __restrict__ packed,
                                                        unsigned int* __restrict__ bucket) {
    if (blockIdx.x >= NB_G1M) {
        // ---- fill branch ----
        int e = (blockIdx.x - NB_G1M) * 256 + threadIdx.x;
        if (e >= N_EDGES) return;
        int r = ei[e];
        int c = ei[N_EDGES + e];
        float w = ew[e];
        unsigned long long add = (1ULL << 40) | (unsigned long long)(unsigned)(w * EW_SCALE + 0.5f);
        unsigned long long old = atomicAdd(&packed[c], add);
        unsigned pos = (unsigned)(old >> 40);
        if (pos < CAP) {
            unsigned short wh = __half_as_ushort(__float2half_rn(w));
            bucket[(size_t)c * CAP + pos] = (unsigned)r | ((unsigned)wh << 16);
        }
        return;
    }

    // ---- MFMA gemm1 branch: rows blockIdx*64 + wv*16 ----
    const int wv   = threadIdx.x >> 6;
    const int lane = threadIdx.x & 63;
    const int quad = lane >> 4;
    const int l16  = lane & 15;
    const int row0 = blockIdx.x * 64 + wv * 16;
    if (row0 >= N_NODES) return;           // tail: 50000 = 781*64 + 16

    float4v acc[8] = {};
#pragma unroll
    for (int kc = 0; kc < 4; kc++) {
        const int k0 = kc * 32;
        const float* xp = X + (size_t)(row0 + l16) * 128 + k0 + quad * 8;
        float4 a0 = *(const float4*)xp;
        float4 a1 = *(const float4*)(xp + 4);
        half8 a;
        a[0] = (_Float16)a0.x; a[1] = (_Float16)a0.y;
        a[2] = (_Float16)a0.z; a[3] = (_Float16)a0.w;
        a[4] = (_Float16)a1.x; a[5] = (_Float16)a1.y;
        a[6] = (_Float16)a1.z; a[7] = (_Float16)a1.w;
#pragma unroll
        for (int ct = 0; ct < 8; ct++) {
            const float* wp = W + (size_t)(k0 + quad * 8) * 128 + ct * 16 + l16;
            half8 b;
#pragma unroll
            for (int j = 0; j < 8; j++) b[j] = (_Float16)wp[j * 128];
            acc[ct] = __builtin_amdgcn_mfma_f32_16x16x32_f16(a, b, acc[ct], 0, 0, 0);
        }
    }
#pragma unroll
    for (int r = 0; r < 4; r++) {
        int row = row0 + quad * 4 + r;
#pragma unroll
        for (int ct = 0; ct < 8; ct++) {
            Yh[(size_t)row * 128 + ct * 16 + l16] = __float2half_rn(acc[ct][r]);
        }
    }
}

// ---------------------------------------------------------------------------
// Layer-1 agg + row-local gemm2 fusion. 512 threads = 8 waves; 16 nodes/block,
// 2 serial nodes/wave; UNROLL-8 gather (8 outstanding loads per chain).
// cnt/dinv read directly from packed. h1 staged in LDS; MFMA col-tile wv.
// ---------------------------------------------------------------------------
__global__ __launch_bounds__(512) void agg1_gemm2_kernel(const __half* __restrict__ xw1,
                                                         const unsigned long long* __restrict__ packed,
                                                         const unsigned int* __restrict__ bucket,
                                                         const float* __restrict__ b1,
                                                         const float* __restrict__ W2,
                                                         __half* __restrict__ x2) {
    __shared__ _Float16 sh1[16][136];
    const int wv   = threadIdx.x >> 6;     // 0..7
    const int lane = threadIdx.x & 63;
    const unsigned int* xh = (const unsigned int*)xw1;
    const int node0 = blockIdx.x * 16;

    float2 bb = ((const float2*)b1)[lane];

#pragma unroll
    for (int j = 0; j < 2; j++) {
        int node = node0 + wv * 2 + j;
        int n; float dv;
        unpack_pd(packed[node], n, dv);

        unsigned pk = 0u;
        if (lane < n) {
            unsigned eh = bucket[(size_t)node * CAP + lane];
            int src = eh & 0xFFFFu;
            int sn; float sdv;
            unpack_pd(packed[src], sn, sdv);
            float v = hu2f((unsigned short)(eh >> 16)) * sdv;
            pk = (unsigned)src | ((unsigned)__half_as_ushort(__float2half_rn(v)) << 16);
        }
        int pki = (int)pk;

        float2 xs = h2f(xh[(size_t)node * 64 + lane]);
        float accx = dv * xs.x;
        float accy = dv * xs.y;

        int i = 0;
        for (; i + 7 < n; i += 8) {
            unsigned u0 = (unsigned)__shfl(pki, i);
            unsigned u1 = (unsigned)__shfl(pki, i + 1);
            unsigned u2 = (unsigned)__shfl(pki, i + 2);
            unsigned u3 = (unsigned)__shfl(pki, i + 3);
            unsigned u4 = (unsigned)__shfl(pki, i + 4);
            unsigned u5 = (unsigned)__shfl(pki, i + 5);
            unsigned u6 = (unsigned)__shfl(pki, i + 6);
            unsigned u7 = (unsigned)__shfl(pki, i + 7);
            float2 f0 = h2f(xh[(size_t)(u0 & 0xFFFF) * 64 + lane]);
            float2 f1 = h2f(xh[(size_t)(u1 & 0xFFFF) * 64 + lane]);
            float2 f2 = h2f(xh[(size_t)(u2 & 0xFFFF) * 64 + lane]);
            float2 f3 = h2f(xh[(size_t)(u3 & 0xFFFF) * 64 + lane]);
            float2 f4 = h2f(xh[(size_t)(u4 & 0xFFFF) * 64 + lane]);
            float2 f5 = h2f(xh[(size_t)(u5 & 0xFFFF) * 64 + lane]);
            float2 f6 = h2f(xh[(size_t)(u6 & 0xFFFF) * 64 + lane]);
            float2 f7 = h2f(xh[(size_t)(u7 & 0xFFFF) * 64 + lane]);
            float v0 = hu2f((unsigned short)(u0 >> 16));
            float v1 = hu2f((unsigned short)(u1 >> 16));
            float v2 = hu2f((unsigned short)(u2 >> 16));
            float v3 = hu2f((unsigned short)(u3 >> 16));
            float v4 = hu2f((unsigned short)(u4 >> 16));
            float v5 = hu2f((unsigned short)(u5 >> 16));
            float v6 = hu2f((unsigned short)(u6 >> 16));
            float v7 = hu2f((unsigned short)(u7 >> 16));
            accx += v0*f0.x + v1*f1.x + v2*f2.x + v3*f3.x
                  + v4*f4.x + v5*f5.x + v6*f6.x + v7*f7.x;
            accy += v0*f0.y + v1*f1.y + v2*f2.y + v3*f3.y
                  + v4*f4.y + v5*f5.y + v6*f6.y + v7*f7.y;
        }
        for (; i < n; i++) {
            unsigned u0 = (unsigned)__shfl(pki, i);
            float v0 = hu2f((unsigned short)(u0 >> 16));
            float2 f0 = h2f(xh[(size_t)(u0 & 0xFFFF) * 64 + lane]);
            accx += v0 * f0.x;
            accy += v0 * f0.y;
        }

        float hx = fmaxf(dv * accx + bb.x, 0.0f);
        float hy = fmaxf(dv * accy + bb.y, 0.0f);
        int lr = wv * 2 + j;
        sh1[lr][lane * 2]     = (_Float16)hx;
        sh1[lr][lane * 2 + 1] = (_Float16)hy;
    }
    __syncthreads();

    // --- MFMA: rows node0..node0+15; wave wv computes col-tile wv (16 cols).
    const int quad = lane >> 4;
    const int l16  = lane & 15;
    float4v acc0 = {};
#pragma unroll
    for (int kc = 0; kc < 4; kc++) {
        const int k0 = kc * 32;
        half8 a = *(const half8*)(&sh1[l16][k0 + quad * 8]);
        const float* wp = W2 + (size_t)(k0 + quad * 8) * 128 + wv * 16 + l16;
        half8 b;
#pragma unroll
        for (int jj = 0; jj < 8; jj++) b[jj] = (_Float16)wp[jj * 128];
        acc0 = __builtin_amdgcn_mfma_f32_16x16x32_f16(a, b, acc0, 0, 0, 0);
    }
#pragma unroll
    for (int r = 0; r < 4; r++) {
        int row = node0 + quad * 4 + r;
        int rn; float s;
        unpack_pd(packed[row], rn, s);
        x2[(size_t)row * 128 + wv * 16 + l16] = __float2half_rn(acc0[r] * s);
    }
}

// ---------------------------------------------------------------------------
// Layer-2 aggregation FUSED with head dot: nodedot[c] = relu(h2[c]) . Wh
// UNROLL-8 gather. Plain store, no fences.
// ---------------------------------------------------------------------------
__global__ __launch_bounds__(256) void agg_head_kernel(const __half* __restrict__ xwh,
                                                       const unsigned long long* __restrict__ packed,
                                                       const unsigned int* __restrict__ bucket,
                                                       const float* __restrict__ bias,
                                                       const float* __restrict__ Wh,
                                                       float* __restrict__ nodedot) {
    int node = blockIdx.x * 4 + (threadIdx.x >> 6);
    int lane = threadIdx.x & 63;
    const unsigned int* xh = (const unsigned int*)xwh;

    int n; float dv;
    unpack_pd(packed[node], n, dv);

    unsigned int ehdr = (lane < n) ? bucket[(size_t)node * CAP + lane] : 0u;
    int eh = (int)ehdr;

    float2 xs = h2f(xh[(size_t)node * 64 + lane]);
    float accx = xs.x;
    float accy = xs.y;

    int i = 0;
    for (; i + 7 < n; i += 8) {
        unsigned u0 = (unsigned)__shfl(eh, i);
        unsigned u1 = (unsigned)__shfl(eh, i + 1);
        unsigned u2 = (unsigned)__shfl(eh, i + 2);
        unsigned u3 = (unsigned)__shfl(eh, i + 3);
        unsigned u4 = (unsigned)__shfl(eh, i + 4);
        unsigned u5 = (unsigned)__shfl(eh, i + 5);
        unsigned u6 = (unsigned)__shfl(eh, i + 6);
        unsigned u7 = (unsigned)__shfl(eh, i + 7);
        float2 f0 = h2f(xh[(size_t)(u0 & 0xFFFF) * 64 + lane]);
        float2 f1 = h2f(xh[(size_t)(u1 & 0xFFFF) * 64 + lane]);
        float2 f2 = h2f(xh[(size_t)(u2 & 0xFFFF) * 64 + lane]);
        float2 f3 = h2f(xh[(size_t)(u3 & 0xFFFF) * 64 + lane]);
        float2 f4 = h2f(xh[(size_t)(u4 & 0xFFFF) * 64 + lane]);
        float2 f5 = h2f(xh[(size_t)(u5 & 0xFFFF) * 64 + lane]);
        float2 f6 = h2f(xh[(size_t)(u6 & 0xFFFF) * 64 + lane]);
        float2 f7 = h2f(xh[(size_t)(u7 & 0xFFFF) * 64 + lane]);
        float v0 = hu2f((unsigned short)(u0 >> 16));
        float v1 = hu2f((unsigned short)(u1 >> 16));
        float v2 = hu2f((unsigned short)(u2 >> 16));
        float v3 = hu2f((unsigned short)(u3 >> 16));
        float v4 = hu2f((unsigned short)(u4 >> 16));
        float v5 = hu2f((unsigned short)(u5 >> 16));
        float v6 = hu2f((unsigned short)(u6 >> 16));
        float v7 = hu2f((unsigned short)(u7 >> 16));
        accx += v0*f0.x + v1*f1.x + v2*f2.x + v3*f3.x
              + v4*f4.x + v5*f5.x + v6*f6.x + v7*f7.x;
        accy += v0*f0.y + v1*f1.y + v2*f2.y + v3*f3.y
              + v4*f4.y + v5*f5.y + v6*f6.y + v7*f7.y;
    }
    for (; i < n; i++) {
        unsigned u0 = (unsigned)__shfl(eh, i);
        float v0 = hu2f((unsigned short)(u0 >> 16));
        float2 f0 = h2f(xh[(size_t)(u0 & 0xFFFF) * 64 + lane]);
        accx += v0 * f0.x;
        accy += v0 * f0.y;
    }

    float2 b = ((const float2*)bias)[lane];
    float hx = fmaxf(dv * accx + b.x, 0.0f);
    float hy = fmaxf(dv * accy + b.y, 0.0f);
    float2 w = ((const float2*)Wh)[lane];
    float s = hx * w.x + hy * w.y;
#pragma unroll
    for (int off = 32; off > 0; off >>= 1) s += __shfl_down(s, off, 64);
    if (lane == 0) nodedot[node] = s;
}

// ---------------------------------------------------------------------------
// out[g] = (sum nodedot over graph)/cnt + bh; bounds via binary search.
// ---------------------------------------------------------------------------
__global__ __launch_bounds__(256) void final2_kernel(const float* __restrict__ nodedot,
                                                     const int* __restrict__ batch,
                                                     const float* __restrict__ bh,
                                                     float* __restrict__ out) {
    __shared__ float red[256];
    int g = blockIdx.x;
    int lo = 0, hi = N_NODES;
    while (lo < hi) { int mid = (lo + hi) >> 1; if (batch[mid] < g) lo = mid + 1; else hi = mid; }
    int a = lo;
    hi = N_NODES;
    while (lo < hi) { int mid = (lo + hi) >> 1; if (batch[mid] < g + 1) lo = mid + 1; else hi = mid; }
    int b = lo;

    float s = 0.0f;
    for (int n = a + threadIdx.x; n < b; n += 256) s += nodedot[n];
    red[threadIdx.x] = s;
    __syncthreads();
#pragma unroll
    for (int off = 128; off > 0; off >>= 1) {
        if (threadIdx.x < off) red[threadIdx.x] += red[threadIdx.x + off];
        __syncthreads();
    }
    if (threadIdx.x == 0)
        out[g] = red[0] / fmaxf((float)(b - a), 1.0f) + bh[0];
}

// ---------------------------------------------------------------------------
extern "C" void kernel_launch(void* const* d_in, const int* in_sizes, int n_in,
                              void* d_out, int out_size, void* d_ws, size_t ws_size,
                              hipStream_t stream) {
    const float* x   = (const float*)d_in[0];
    const float* ew  = (const float*)d_in[1];
    const float* W1  = (const float*)d_in[2];
    const float* b1  = (const float*)d_in[3];
    const float* W2  = (const float*)d_in[4];
    const float* b2  = (const float*)d_in[5];
    const float* Wh  = (const float*)d_in[6];
    const float* bh  = (const float*)d_in[7];
    const int*   ei  = (const int*)d_in[8];
    const int*   bat = (const int*)d_in[9];
    float* out = (float*)d_out;

    char* ws = (char*)d_ws;
    __half* bufAh  = (__half*)ws;                         ws += (size_t)N_NODES * D * 2;
    __half* bufBh  = (__half*)ws;                         ws += (size_t)N_NODES * D * 2;
    unsigned int* bucket = (unsigned int*)ws;             ws += (size_t)N_NODES * CAP * 4;
    unsigned long long* packed = (unsigned long long*)ws; ws += (size_t)N_NODES * 8;
    float*  nodedot = (float*)ws;                         ws += (size_t)N_NODES * 4;

    const int nb_agg4 = N_NODES / 4;                  // 12500

    hipMemsetAsync(packed, 0, (size_t)N_NODES * 8, stream);

    // LDS-free fused: MFMA gemm1 + fill at full occupancy
    fused_gemm1_fill<<<NB_G1M + NB_FILL, 256, 0, stream>>>(x, W1, bufAh, ei, ew, packed, bucket);

    // layer 1 agg + row-local gemm2 fusion -> x2' in bufBh
    agg1_gemm2_kernel<<<NB_AGG16, 512, 0, stream>>>(bufAh, packed, bucket, b1, W2, bufBh);

    // layer 2 agg + head dot
    agg_head_kernel<<<nb_agg4, 256, 0, stream>>>(bufBh, packed, bucket, b2, Wh, nodedot);

    // segment-sum + head bias
    final2_kernel<<<N_GRAPHS, 256, 0, stream>>>(nodedot, bat, bh, out);
}

// Round 18
// 220.547 us; speedup vs baseline: 1.0396x; 1.0396x over previous
//
#include <hip/hip_runtime.h>
#include <hip/hip_bf16.h>
#include <hip/hip_fp16.h>
#include <hip/hip_fp8.h>

#define N_NODES  50000
#define N_EDGES  800000
#define D        128
#define N_GRAPHS 64
#define CAP      64          // bucket capacity; in-deg ~ Poisson(16), P(>=64) ~ 1e-19
#define EW_SCALE 1048576.0f  // 2^20 fixed-point for packed weighted-degree
#define NB_GEMM1 391         // ceil(50000/128)
#define NB_FILL  3125        // 800000/256
#define NB_AGG16 3125        // N_NODES/16

typedef _Float16 half8 __attribute__((ext_vector_type(8)));
typedef float   float4v __attribute__((ext_vector_type(4)));
typedef float   f32x2   __attribute__((ext_vector_type(2)));

__device__ __forceinline__ float2 h2f(unsigned int u) {
    __half2 h = *reinterpret_cast<__half2*>(&u);
    return __half22float2(h);
}
__device__ __forceinline__ unsigned int f2h(float a, float b) {
    __half2 h = __floats2half2_rn(a, b);
    return *reinterpret_cast<unsigned int*>(&h);
}
__device__ __forceinline__ float hu2f(unsigned short u) {
    __half_raw hr; hr.x = u;
    return __half2float(__half(hr));
}
// 2x fp8 e4m3 -> 2x f32 (v_cvt_pk_f32_fp8)
__device__ __forceinline__ float2 fp8x2_f32(unsigned short u) {
    f32x2 v = __builtin_amdgcn_cvt_pk_f32_fp8((int)u, false);
    return make_float2(v[0], v[1]);
}
__device__ __forceinline__ unsigned char f32_fp8(float f) {
    __hip_fp8_e4m3 q(f);
    return (unsigned char)q.__x;
}
// unpack packed word -> (cnt, dinv)
__device__ __forceinline__ void unpack_pd(unsigned long long p, int& n, float& dv) {
    int c = (int)(p >> 40);
    n = c < CAP ? c : CAP;
    dv = rsqrtf(1.0f + (float)(p & 0xFFFFFFFFFFULL) * (1.0f / EW_SCALE));
}

// ---------------------------------------------------------------------------
// FUSED (r16 structure): blocks [0,391) = gemm1 (fp32 x @ W1 -> fp16, BK=32,
// LDS=32KB); blocks [391,3516) = fill (1 edge/thread, returning 64-bit atomic
// on 50K spread counters). Bucket entry 4B: src:u16 | ew:fp16.
// ---------------------------------------------------------------------------
__global__ __launch_bounds__(256) void fused_gemm1_fill(const float* __restrict__ X,
                                                        const float* __restrict__ W,
                                                        __half* __restrict__ Yh,
                                                        const int* __restrict__ ei,
                                                        const float* __restrict__ ew,
                                                        unsigned long long* __restrict__ packed,
                                                        unsigned int* __restrict__ bucket) {
    __shared__ float XT[32 * 128];  // 16 KB
    __shared__ float Ws[32 * 128];  // 16 KB

    if (blockIdx.x >= NB_GEMM1) {
        int e = (blockIdx.x - NB_GEMM1) * 256 + threadIdx.x;
        if (e >= N_EDGES) return;
        int r = ei[e];
        int c = ei[N_EDGES + e];
        float w = ew[e];
        unsigned long long add = (1ULL << 40) | (unsigned long long)(unsigned)(w * EW_SCALE + 0.5f);
        unsigned long long old = atomicAdd(&packed[c], add);
        unsigned pos = (unsigned)(old >> 40);
        if (pos < CAP) {
            unsigned short wh = __half_as_ushort(__float2half_rn(w));
            bucket[(size_t)c * CAP + pos] = (unsigned)r | ((unsigned)wh << 16);
        }
        return;
    }

    const int tid  = threadIdx.x;
    const int row0 = blockIdx.x * 128;
    const int tr = tid >> 4, tc = tid & 15;
    float acc[8][8] = {};

    for (int kt = 0; kt < 4; kt++) {
        const int kbase = kt * 32;
        {
            const float4* src = (const float4*)(W + kbase * 128);
            float4* dst = (float4*)Ws;
            for (int i = tid; i < 1024; i += 256) dst[i] = src[i];
        }
        {
            int r  = tid >> 1;
            int rr = row0 + r; if (rr >= N_NODES) rr = N_NODES - 1;
            int k0 = (tid & 1) * 16;
            const float4* src = (const float4*)(X + (size_t)rr * 128 + kbase + k0);
#pragma unroll
            for (int i = 0; i < 4; i++) {
                float4 v = src[i];
                int k = k0 + i * 4;
                XT[(k + 0) * 128 + r] = v.x;
                XT[(k + 1) * 128 + r] = v.y;
                XT[(k + 2) * 128 + r] = v.z;
                XT[(k + 3) * 128 + r] = v.w;
            }
        }
        __syncthreads();
#pragma unroll 4
        for (int k = 0; k < 32; k++) {
            float xs[8], ws[8];
            *(float4*)&xs[0] = *(const float4*)(XT + k * 128 + tr * 8);
            *(float4*)&xs[4] = *(const float4*)(XT + k * 128 + tr * 8 + 4);
            *(float4*)&ws[0] = *(const float4*)(Ws + k * 128 + tc * 8);
            *(float4*)&ws[4] = *(const float4*)(Ws + k * 128 + tc * 8 + 4);
#pragma unroll
            for (int i = 0; i < 8; i++)
#pragma unroll
                for (int j = 0; j < 8; j++)
                    acc[i][j] += xs[i] * ws[j];
        }
        __syncthreads();
    }
#pragma unroll
    for (int i = 0; i < 8; i++) {
        int r = row0 + tr * 8 + i;
        if (r < N_NODES) {
            uint4 p;
            p.x = f2h(acc[i][0], acc[i][1]);
            p.y = f2h(acc[i][2], acc[i][3]);
            p.z = f2h(acc[i][4], acc[i][5]);
            p.w = f2h(acc[i][6], acc[i][7]);
            *(uint4*)(Yh + (size_t)r * 128 + tc * 8) = p;
        }
    }
}

// ---------------------------------------------------------------------------
// Layer-1 agg + row-local gemm2 fusion. 512 threads = 8 waves; 16 nodes/block,
// 2 serial nodes/wave; UNROLL-8 gather. x1 gather stays fp16 (layer-1 errors
// would compound); epilogue writes x2' in FP8 e4m3 (layer-2 gather payload).
// ---------------------------------------------------------------------------
__global__ __launch_bounds__(512) void agg1_gemm2_kernel(const __half* __restrict__ xw1,
                                                         const unsigned long long* __restrict__ packed,
                                                         const unsigned int* __restrict__ bucket,
                                                         const float* __restrict__ b1,
                                                         const float* __restrict__ W2,
                                                         unsigned char* __restrict__ x2) {
    __shared__ _Float16 sh1[16][136];
    const int wv   = threadIdx.x >> 6;     // 0..7
    const int lane = threadIdx.x & 63;
    const unsigned int* xh = (const unsigned int*)xw1;
    const int node0 = blockIdx.x * 16;

    float2 bb = ((const float2*)b1)[lane];

#pragma unroll
    for (int j = 0; j < 2; j++) {
        int node = node0 + wv * 2 + j;
        int n; float dv;
        unpack_pd(packed[node], n, dv);

        unsigned pk = 0u;
        if (lane < n) {
            unsigned eh = bucket[(size_t)node * CAP + lane];
            int src = eh & 0xFFFFu;
            int sn; float sdv;
            unpack_pd(packed[src], sn, sdv);
            float v = hu2f((unsigned short)(eh >> 16)) * sdv;
            pk = (unsigned)src | ((unsigned)__half_as_ushort(__float2half_rn(v)) << 16);
        }
        int pki = (int)pk;

        float2 xs = h2f(xh[(size_t)node * 64 + lane]);
        float accx = dv * xs.x;
        float accy = dv * xs.y;

        int i = 0;
        for (; i + 7 < n; i += 8) {
            unsigned u0 = (unsigned)__shfl(pki, i);
            unsigned u1 = (unsigned)__shfl(pki, i + 1);
            unsigned u2 = (unsigned)__shfl(pki, i + 2);
            unsigned u3 = (unsigned)__shfl(pki, i + 3);
            unsigned u4 = (unsigned)__shfl(pki, i + 4);
            unsigned u5 = (unsigned)__shfl(pki, i + 5);
            unsigned u6 = (unsigned)__shfl(pki, i + 6);
            unsigned u7 = (unsigned)__shfl(pki, i + 7);
            float2 f0 = h2f(xh[(size_t)(u0 & 0xFFFF) * 64 + lane]);
            float2 f1 = h2f(xh[(size_t)(u1 & 0xFFFF) * 64 + lane]);
            float2 f2 = h2f(xh[(size_t)(u2 & 0xFFFF) * 64 + lane]);
            float2 f3 = h2f(xh[(size_t)(u3 & 0xFFFF) * 64 + lane]);
            float2 f4 = h2f(xh[(size_t)(u4 & 0xFFFF) * 64 + lane]);
            float2 f5 = h2f(xh[(size_t)(u5 & 0xFFFF) * 64 + lane]);
            float2 f6 = h2f(xh[(size_t)(u6 & 0xFFFF) * 64 + lane]);
            float2 f7 = h2f(xh[(size_t)(u7 & 0xFFFF) * 64 + lane]);
            float v0 = hu2f((unsigned short)(u0 >> 16));
            float v1 = hu2f((unsigned short)(u1 >> 16));
            float v2 = hu2f((unsigned short)(u2 >> 16));
            float v3 = hu2f((unsigned short)(u3 >> 16));
            float v4 = hu2f((unsigned short)(u4 >> 16));
            float v5 = hu2f((unsigned short)(u5 >> 16));
            float v6 = hu2f((unsigned short)(u6 >> 16));
            float v7 = hu2f((unsigned short)(u7 >> 16));
            accx += v0*f0.x + v1*f1.x + v2*f2.x + v3*f3.x
                  + v4*f4.x + v5*f5.x + v6*f6.x + v7*f7.x;
            accy += v0*f0.y + v1*f1.y + v2*f2.y + v3*f3.y
                  + v4*f4.y + v5*f5.y + v6*f6.y + v7*f7.y;
        }
        for (; i < n; i++) {
            unsigned u0 = (unsigned)__shfl(pki, i);
            float v0 = hu2f((unsigned short)(u0 >> 16));
            float2 f0 = h2f(xh[(size_t)(u0 & 0xFFFF) * 64 + lane]);
            accx += v0 * f0.x;
            accy += v0 * f0.y;
        }

        float hx = fmaxf(dv * accx + bb.x, 0.0f);
        float hy = fmaxf(dv * accy + bb.y, 0.0f);
        int lr = wv * 2 + j;
        sh1[lr][lane * 2]     = (_Float16)hx;
        sh1[lr][lane * 2 + 1] = (_Float16)hy;
    }
    __syncthreads();

    // --- MFMA: rows node0..node0+15; wave wv computes col-tile wv (16 cols).
    const int quad = lane >> 4;
    const int l16  = lane & 15;
    float4v acc0 = {};
#pragma unroll
    for (int kc = 0; kc < 4; kc++) {
        const int k0 = kc * 32;
        half8 a = *(const half8*)(&sh1[l16][k0 + quad * 8]);
        const float* wp = W2 + (size_t)(k0 + quad * 8) * 128 + wv * 16 + l16;
        half8 b;
#pragma unroll
        for (int jj = 0; jj < 8; jj++) b[jj] = (_Float16)wp[jj * 128];
        acc0 = __builtin_amdgcn_mfma_f32_16x16x32_f16(a, b, acc0, 0, 0, 0);
    }
#pragma unroll
    for (int r = 0; r < 4; r++) {
        int row = node0 + quad * 4 + r;
        int rn; float s;
        unpack_pd(packed[row], rn, s);
        x2[(size_t)row * 128 + wv * 16 + l16] = f32_fp8(acc0[r] * s);
    }
}

// ---------------------------------------------------------------------------
// Layer-2 aggregation FUSED with head dot on FP8 x2' (2 fp8/lane = 128B/edge
// gather, 2 cache lines instead of 4). UNROLL-8. Plain store, no fences.
// ---------------------------------------------------------------------------
__global__ __launch_bounds__(256) void agg_head_kernel(const unsigned char* __restrict__ x8,
                                                       const unsigned long long* __restrict__ packed,
                                                       const unsigned int* __restrict__ bucket,
                                                       const float* __restrict__ bias,
                                                       const float* __restrict__ Wh,
                                                       float* __restrict__ nodedot) {
    int node = blockIdx.x * 4 + (threadIdx.x >> 6);
    int lane = threadIdx.x & 63;
    const unsigned short* xs16 = (const unsigned short*)x8;  // 2 fp8 per ushort

    int n; float dv;
    unpack_pd(packed[node], n, dv);

    unsigned int ehdr = (lane < n) ? bucket[(size_t)node * CAP + lane] : 0u;
    int eh = (int)ehdr;

    float2 xs = fp8x2_f32(xs16[(size_t)node * 64 + lane]);
    float accx = xs.x;
    float accy = xs.y;

    int i = 0;
    for (; i + 7 < n; i += 8) {
        unsigned u0 = (unsigned)__shfl(eh, i);
        unsigned u1 = (unsigned)__shfl(eh, i + 1);
        unsigned u2 = (unsigned)__shfl(eh, i + 2);
        unsigned u3 = (unsigned)__shfl(eh, i + 3);
        unsigned u4 = (unsigned)__shfl(eh, i + 4);
        unsigned u5 = (unsigned)__shfl(eh, i + 5);
        unsigned u6 = (unsigned)__shfl(eh, i + 6);
        unsigned u7 = (unsigned)__shfl(eh, i + 7);
        unsigned short m0 = xs16[(size_t)(u0 & 0xFFFF) * 64 + lane];
        unsigned short m1 = xs16[(size_t)(u1 & 0xFFFF) * 64 + lane];
        unsigned short m2 = xs16[(size_t)(u2 & 0xFFFF) * 64 + lane];
        unsigned short m3 = xs16[(size_t)(u3 & 0xFFFF) * 64 + lane];
        unsigned short m4 = xs16[(size_t)(u4 & 0xFFFF) * 64 + lane];
        unsigned short m5 = xs16[(size_t)(u5 & 0xFFFF) * 64 + lane];
        unsigned short m6 = xs16[(size_t)(u6 & 0xFFFF) * 64 + lane];
        unsigned short m7 = xs16[(size_t)(u7 & 0xFFFF) * 64 + lane];
        float2 f0 = fp8x2_f32(m0);
        float2 f1 = fp8x2_f32(m1);
        float2 f2 = fp8x2_f32(m2);
        float2 f3 = fp8x2_f32(m3);
        float2 f4 = fp8x2_f32(m4);
        float2 f5 = fp8x2_f32(m5);
        float2 f6 = fp8x2_f32(m6);
        float2 f7 = fp8x2_f32(m7);
        float v0 = hu2f((unsigned short)(u0 >> 16));
        float v1 = hu2f((unsigned short)(u1 >> 16));
        float v2 = hu2f((unsigned short)(u2 >> 16));
        float v3 = hu2f((unsigned short)(u3 >> 16));
        float v4 = hu2f((unsigned short)(u4 >> 16));
        float v5 = hu2f((unsigned short)(u5 >> 16));
        float v6 = hu2f((unsigned short)(u6 >> 16));
        float v7 = hu2f((unsigned short)(u7 >> 16));
        accx += v0*f0.x + v1*f1.x + v2*f2.x + v3*f3.x
              + v4*f4.x + v5*f5.x + v6*f6.x + v7*f7.x;
        accy += v0*f0.y + v1*f1.y + v2*f2.y + v3*f3.y
              + v4*f4.y + v5*f5.y + v6*f6.y + v7*f7.y;
    }
    for (; i < n; i++) {
        unsigned u0 = (unsigned)__shfl(eh, i);
        float v0 = hu2f((unsigned short)(u0 >> 16));
        float2 f0 = fp8x2_f32(xs16[(size_t)(u0 & 0xFFFF) * 64 + lane]);
        accx += v0 * f0.x;
        accy += v0 * f0.y;
    }

    float2 b = ((const float2*)bias)[lane];
    float hx = fmaxf(dv * accx + b.x, 0.0f);
    float hy = fmaxf(dv * accy + b.y, 0.0f);
    float2 w = ((const float2*)Wh)[lane];
    float s = hx * w.x + hy * w.y;
#pragma unroll
    for (int off = 32; off > 0; off >>= 1) s += __shfl_down(s, off, 64);
    if (lane == 0) nodedot[node] = s;
}

// ---------------------------------------------------------------------------
// out[g] = (sum nodedot over graph)/cnt + bh; bounds via binary search.
// ---------------------------------------------------------------------------
__global__ __launch_bounds__(256) void final2_kernel(const float* __restrict__ nodedot,
                                                     const int* __restrict__ batch,
                                                     const float* __restrict__ bh,
                                                     float* __restrict__ out) {
    __shared__ float red[256];
    int g = blockIdx.x;
    int lo = 0, hi = N_NODES;
    while (lo < hi) { int mid = (lo + hi) >> 1; if (batch[mid] < g) lo = mid + 1; else hi = mid; }
    int a = lo;
    hi = N_NODES;
    while (lo < hi) { int mid = (lo + hi) >> 1; if (batch[mid] < g + 1) lo = mid + 1; else hi = mid; }
    int b = lo;

    float s = 0.0f;
    for (int n = a + threadIdx.x; n < b; n += 256) s += nodedot[n];
    red[threadIdx.x] = s;
    __syncthreads();
#pragma unroll
    for (int off = 128; off > 0; off >>= 1) {
        if (threadIdx.x < off) red[threadIdx.x] += red[threadIdx.x + off];
        __syncthreads();
    }
    if (threadIdx.x == 0)
        out[g] = red[0] / fmaxf((float)(b - a), 1.0f) + bh[0];
}

// ---------------------------------------------------------------------------
extern "C" void kernel_launch(void* const* d_in, const int* in_sizes, int n_in,
                              void* d_out, int out_size, void* d_ws, size_t ws_size,
                              hipStream_t stream) {
    const float* x   = (const float*)d_in[0];
    const float* ew  = (const float*)d_in[1];
    const float* W1  = (const float*)d_in[2];
    const float* b1  = (const float*)d_in[3];
    const float* W2  = (const float*)d_in[4];
    const float* b2  = (const float*)d_in[5];
    const float* Wh  = (const float*)d_in[6];
    const float* bh  = (const float*)d_in[7];
    const int*   ei  = (const int*)d_in[8];
    const int*   bat = (const int*)d_in[9];
    float* out = (float*)d_out;

    char* ws = (char*)d_ws;
    __half* bufAh  = (__half*)ws;                         ws += (size_t)N_NODES * D * 2;
    unsigned char* bufB8 = (unsigned char*)ws;            ws += (size_t)N_NODES * D;
    ws += 128 - ((size_t)ws & 127);                       // realign
    unsigned int* bucket = (unsigned int*)ws;             ws += (size_t)N_NODES * CAP * 4;
    unsigned long long* packed = (unsigned long long*)ws; ws += (size_t)N_NODES * 8;
    float*  nodedot = (float*)ws;                         ws += (size_t)N_NODES * 4;

    const int nb_agg4 = N_NODES / 4;                  // 12500

    hipMemsetAsync(packed, 0, (size_t)N_NODES * 8, stream);

    // gemm1 (x@W1 -> fp16, BK=32 LDS) overlapped with fill (atomic-floor-bound)
    fused_gemm1_fill<<<NB_GEMM1 + NB_FILL, 256, 0, stream>>>(x, W1, bufAh, ei, ew, packed, bucket);

    // layer 1 agg + row-local gemm2 fusion -> x2' (fp8) in bufB8
    agg1_gemm2_kernel<<<NB_AGG16, 512, 0, stream>>>(bufAh, packed, bucket, b1, W2, bufB8);

    // layer 2 agg (fp8 gather, 2 lines/edge) + head dot
    agg_head_kernel<<<nb_agg4, 256, 0, stream>>>(bufB8, packed, bucket, b2, Wh, nodedot);

    // segment-sum + head bias
    final2_kernel<<<N_GRAPHS, 256, 0, stream>>>(nodedot, bat, bh, out);
}

// Round 19
// 216.917 us; speedup vs baseline: 1.0570x; 1.0167x over previous
//
#include <hip/hip_runtime.h>
#include <hip/hip_bf16.h>
#include <hip/hip_fp16.h>
#include <hip/hip_fp8.h>

#define N_NODES  50000
#define N_EDGES  800000
#define D        128
#define N_GRAPHS 64
#define CAP      64          // bucket capacity; in-deg ~ Poisson(16), P(>=64) ~ 1e-19
#define EW_SCALE 1048576.0f  // 2^20 fixed-point for packed weighted-degree
#define NB_GEMM1 391         // ceil(50000/128)
#define NB_FILL  3125        // 800000/256
#define NB_AGG16 3125        // N_NODES/16

typedef _Float16 half8 __attribute__((ext_vector_type(8)));
typedef float   float4v __attribute__((ext_vector_type(4)));
typedef float   f32x2   __attribute__((ext_vector_type(2)));

__device__ __forceinline__ float2 h2f(unsigned int u) {
    __half2 h = *reinterpret_cast<__half2*>(&u);
    return __half22float2(h);
}
__device__ __forceinline__ unsigned int f2h(float a, float b) {
    __half2 h = __floats2half2_rn(a, b);
    return *reinterpret_cast<unsigned int*>(&h);
}
__device__ __forceinline__ float hu2f(unsigned short u) {
    __half_raw hr; hr.x = u;
    return __half2float(__half(hr));
}
// 2x fp8 e4m3 -> 2x f32 (v_cvt_pk_f32_fp8)
__device__ __forceinline__ float2 fp8x2_f32(unsigned short u) {
    f32x2 v = __builtin_amdgcn_cvt_pk_f32_fp8((int)u, false);
    return make_float2(v[0], v[1]);
}
__device__ __forceinline__ unsigned char f32_fp8(float f) {
    __hip_fp8_e4m3 q(f);
    return (unsigned char)q.__x;
}
// unpack packed word -> (cnt, dinv)
__device__ __forceinline__ void unpack_pd(unsigned long long p, int& n, float& dv) {
    int c = (int)(p >> 40);
    n = c < CAP ? c : CAP;
    dv = rsqrtf(1.0f + (float)(p & 0xFFFFFFFFFFULL) * (1.0f / EW_SCALE));
}

// ---------------------------------------------------------------------------
// FUSED: blocks [0,391) = gemm1 (fp32 x @ W1 -> FP8 e4m3, BK=32, LDS=32KB);
// blocks [391,3516) = fill (1 edge/thread, returning 64-bit atomic on 50K
// spread counters). Bucket entry 4B: src:u16 | ew:fp16.
// ---------------------------------------------------------------------------
__global__ __launch_bounds__(256) void fused_gemm1_fill(const float* __restrict__ X,
                                                        const float* __restrict__ W,
                                                        unsigned char* __restrict__ Y8,
                                                        const int* __restrict__ ei,
                                                        const float* __restrict__ ew,
                                                        unsigned long long* __restrict__ packed,
                                                        unsigned int* __restrict__ bucket) {
    __shared__ float XT[32 * 128];  // 16 KB
    __shared__ float Ws[32 * 128];  // 16 KB

    if (blockIdx.x >= NB_GEMM1) {
        int e = (blockIdx.x - NB_GEMM1) * 256 + threadIdx.x;
        if (e >= N_EDGES) return;
        int r = ei[e];
        int c = ei[N_EDGES + e];
        float w = ew[e];
        unsigned long long add = (1ULL << 40) | (unsigned long long)(unsigned)(w * EW_SCALE + 0.5f);
        unsigned long long old = atomicAdd(&packed[c], add);
        unsigned pos = (unsigned)(old >> 40);
        if (pos < CAP) {
            unsigned short wh = __half_as_ushort(__float2half_rn(w));
            bucket[(size_t)c * CAP + pos] = (unsigned)r | ((unsigned)wh << 16);
        }
        return;
    }

    const int tid  = threadIdx.x;
    const int row0 = blockIdx.x * 128;
    const int tr = tid >> 4, tc = tid & 15;
    float acc[8][8] = {};

    for (int kt = 0; kt < 4; kt++) {
        const int kbase = kt * 32;
        {
            const float4* src = (const float4*)(W + kbase * 128);
            float4* dst = (float4*)Ws;
            for (int i = tid; i < 1024; i += 256) dst[i] = src[i];
        }
        {
            int r  = tid >> 1;
            int rr = row0 + r; if (rr >= N_NODES) rr = N_NODES - 1;
            int k0 = (tid & 1) * 16;
            const float4* src = (const float4*)(X + (size_t)rr * 128 + kbase + k0);
#pragma unroll
            for (int i = 0; i < 4; i++) {
                float4 v = src[i];
                int k = k0 + i * 4;
                XT[(k + 0) * 128 + r] = v.x;
                XT[(k + 1) * 128 + r] = v.y;
                XT[(k + 2) * 128 + r] = v.z;
                XT[(k + 3) * 128 + r] = v.w;
            }
        }
        __syncthreads();
#pragma unroll 4
        for (int k = 0; k < 32; k++) {
            float xs[8], ws[8];
            *(float4*)&xs[0] = *(const float4*)(XT + k * 128 + tr * 8);
            *(float4*)&xs[4] = *(const float4*)(XT + k * 128 + tr * 8 + 4);
            *(float4*)&ws[0] = *(const float4*)(Ws + k * 128 + tc * 8);
            *(float4*)&ws[4] = *(const float4*)(Ws + k * 128 + tc * 8 + 4);
#pragma unroll
            for (int i = 0; i < 8; i++)
#pragma unroll
                for (int j = 0; j < 8; j++)
                    acc[i][j] += xs[i] * ws[j];
        }
        __syncthreads();
    }
#pragma unroll
    for (int i = 0; i < 8; i++) {
        int r = row0 + tr * 8 + i;
        if (r < N_NODES) {
            uint2 p;
            p.x = (unsigned)f32_fp8(acc[i][0]) | ((unsigned)f32_fp8(acc[i][1]) << 8)
                | ((unsigned)f32_fp8(acc[i][2]) << 16) | ((unsigned)f32_fp8(acc[i][3]) << 24);
            p.y = (unsigned)f32_fp8(acc[i][4]) | ((unsigned)f32_fp8(acc[i][5]) << 8)
                | ((unsigned)f32_fp8(acc[i][6]) << 16) | ((unsigned)f32_fp8(acc[i][7]) << 24);
            *(uint2*)(Y8 + (size_t)r * 128 + tc * 8) = p;
        }
    }
}

// ---------------------------------------------------------------------------
// Layer-1 agg + row-local gemm2 fusion. 512 threads = 8 waves; 16 nodes/block,
// 2 serial nodes/wave; UNROLL-8 FP8 gather (2 lines/edge). h1 accumulated in
// f32, staged fp16 in LDS; MFMA col-tile wv; epilogue writes x2' in FP8.
// ---------------------------------------------------------------------------
__global__ __launch_bounds__(512) void agg1_gemm2_kernel(const unsigned char* __restrict__ x8in,
                                                         const unsigned long long* __restrict__ packed,
                                                         const unsigned int* __restrict__ bucket,
                                                         const float* __restrict__ b1,
                                                         const float* __restrict__ W2,
                                                         unsigned char* __restrict__ x2) {
    __shared__ _Float16 sh1[16][136];
    const int wv   = threadIdx.x >> 6;     // 0..7
    const int lane = threadIdx.x & 63;
    const unsigned short* xs16 = (const unsigned short*)x8in;  // 2 fp8 per ushort
    const int node0 = blockIdx.x * 16;

    float2 bb = ((const float2*)b1)[lane];

#pragma unroll
    for (int j = 0; j < 2; j++) {
        int node = node0 + wv * 2 + j;
        int n; float dv;
        unpack_pd(packed[node], n, dv);

        unsigned pk = 0u;
        if (lane < n) {
            unsigned eh = bucket[(size_t)node * CAP + lane];
            int src = eh & 0xFFFFu;
            int sn; float sdv;
            unpack_pd(packed[src], sn, sdv);
            float v = hu2f((unsigned short)(eh >> 16)) * sdv;
            pk = (unsigned)src | ((unsigned)__half_as_ushort(__float2half_rn(v)) << 16);
        }
        int pki = (int)pk;

        float2 xs = fp8x2_f32(xs16[(size_t)node * 64 + lane]);
        float accx = dv * xs.x;
        float accy = dv * xs.y;

        int i = 0;
        for (; i + 7 < n; i += 8) {
            unsigned u0 = (unsigned)__shfl(pki, i);
            unsigned u1 = (unsigned)__shfl(pki, i + 1);
            unsigned u2 = (unsigned)__shfl(pki, i + 2);
            unsigned u3 = (unsigned)__shfl(pki, i + 3);
            unsigned u4 = (unsigned)__shfl(pki, i + 4);
            unsigned u5 = (unsigned)__shfl(pki, i + 5);
            unsigned u6 = (unsigned)__shfl(pki, i + 6);
            unsigned u7 = (unsigned)__shfl(pki, i + 7);
            unsigned short m0 = xs16[(size_t)(u0 & 0xFFFF) * 64 + lane];
            unsigned short m1 = xs16[(size_t)(u1 & 0xFFFF) * 64 + lane];
            unsigned short m2 = xs16[(size_t)(u2 & 0xFFFF) * 64 + lane];
            unsigned short m3 = xs16[(size_t)(u3 & 0xFFFF) * 64 + lane];
            unsigned short m4 = xs16[(size_t)(u4 & 0xFFFF) * 64 + lane];
            unsigned short m5 = xs16[(size_t)(u5 & 0xFFFF) * 64 + lane];
            unsigned short m6 = xs16[(size_t)(u6 & 0xFFFF) * 64 + lane];
            unsigned short m7 = xs16[(size_t)(u7 & 0xFFFF) * 64 + lane];
            float2 f0 = fp8x2_f32(m0);
            float2 f1 = fp8x2_f32(m1);
            float2 f2 = fp8x2_f32(m2);
            float2 f3 = fp8x2_f32(m3);
            float2 f4 = fp8x2_f32(m4);
            float2 f5 = fp8x2_f32(m5);
            float2 f6 = fp8x2_f32(m6);
            float2 f7 = fp8x2_f32(m7);
            float v0 = hu2f((unsigned short)(u0 >> 16));
            float v1 = hu2f((unsigned short)(u1 >> 16));
            float v2 = hu2f((unsigned short)(u2 >> 16));
            float v3 = hu2f((unsigned short)(u3 >> 16));
            float v4 = hu2f((unsigned short)(u4 >> 16));
            float v5 = hu2f((unsigned short)(u5 >> 16));
            float v6 = hu2f((unsigned short)(u6 >> 16));
            float v7 = hu2f((unsigned short)(u7 >> 16));
            accx += v0*f0.x + v1*f1.x + v2*f2.x + v3*f3.x
                  + v4*f4.x + v5*f5.x + v6*f6.x + v7*f7.x;
            accy += v0*f0.y + v1*f1.y + v2*f2.y + v3*f3.y
                  + v4*f4.y + v5*f5.y + v6*f6.y + v7*f7.y;
        }
        for (; i < n; i++) {
            unsigned u0 = (unsigned)__shfl(pki, i);
            float v0 = hu2f((unsigned short)(u0 >> 16));
            float2 f0 = fp8x2_f32(xs16[(size_t)(u0 & 0xFFFF) * 64 + lane]);
            accx += v0 * f0.x;
            accy += v0 * f0.y;
        }

        float hx = fmaxf(dv * accx + bb.x, 0.0f);
        float hy = fmaxf(dv * accy + bb.y, 0.0f);
        int lr = wv * 2 + j;
        sh1[lr][lane * 2]     = (_Float16)hx;
        sh1[lr][lane * 2 + 1] = (_Float16)hy;
    }
    __syncthreads();

    // --- MFMA: rows node0..node0+15; wave wv computes col-tile wv (16 cols).
    const int quad = lane >> 4;
    const int l16  = lane & 15;
    float4v acc0 = {};
#pragma unroll
    for (int kc = 0; kc < 4; kc++) {
        const int k0 = kc * 32;
        half8 a = *(const half8*)(&sh1[l16][k0 + quad * 8]);
        const float* wp = W2 + (size_t)(k0 + quad * 8) * 128 + wv * 16 + l16;
        half8 b;
#pragma unroll
        for (int jj = 0; jj < 8; jj++) b[jj] = (_Float16)wp[jj * 128];
        acc0 = __builtin_amdgcn_mfma_f32_16x16x32_f16(a, b, acc0, 0, 0, 0);
    }
#pragma unroll
    for (int r = 0; r < 4; r++) {
        int row = node0 + quad * 4 + r;
        int rn; float s;
        unpack_pd(packed[row], rn, s);
        x2[(size_t)row * 128 + wv * 16 + l16] = f32_fp8(acc0[r] * s);
    }
}

// ---------------------------------------------------------------------------
// Layer-2 aggregation FUSED with head dot on FP8 x2' (2 lines/edge gather).
// UNROLL-8. Plain store, no fences.
// ---------------------------------------------------------------------------
__global__ __launch_bounds__(256) void agg_head_kernel(const unsigned char* __restrict__ x8,
                                                       const unsigned long long* __restrict__ packed,
                                                       const unsigned int* __restrict__ bucket,
                                                       const float* __restrict__ bias,
                                                       const float* __restrict__ Wh,
                                                       float* __restrict__ nodedot) {
    int node = blockIdx.x * 4 + (threadIdx.x >> 6);
    int lane = threadIdx.x & 63;
    const unsigned short* xs16 = (const unsigned short*)x8;

    int n; float dv;
    unpack_pd(packed[node], n, dv);

    unsigned int ehdr = (lane < n) ? bucket[(size_t)node * CAP + lane] : 0u;
    int eh = (int)ehdr;

    float2 xs = fp8x2_f32(xs16[(size_t)node * 64 + lane]);
    float accx = xs.x;
    float accy = xs.y;

    int i = 0;
    for (; i + 7 < n; i += 8) {
        unsigned u0 = (unsigned)__shfl(eh, i);
        unsigned u1 = (unsigned)__shfl(eh, i + 1);
        unsigned u2 = (unsigned)__shfl(eh, i + 2);
        unsigned u3 = (unsigned)__shfl(eh, i + 3);
        unsigned u4 = (unsigned)__shfl(eh, i + 4);
        unsigned u5 = (unsigned)__shfl(eh, i + 5);
        unsigned u6 = (unsigned)__shfl(eh, i + 6);
        unsigned u7 = (unsigned)__shfl(eh, i + 7);
        unsigned short m0 = xs16[(size_t)(u0 & 0xFFFF) * 64 + lane];
        unsigned short m1 = xs16[(size_t)(u1 & 0xFFFF) * 64 + lane];
        unsigned short m2 = xs16[(size_t)(u2 & 0xFFFF) * 64 + lane];
        unsigned short m3 = xs16[(size_t)(u3 & 0xFFFF) * 64 + lane];
        unsigned short m4 = xs16[(size_t)(u4 & 0xFFFF) * 64 + lane];
        unsigned short m5 = xs16[(size_t)(u5 & 0xFFFF) * 64 + lane];
        unsigned short m6 = xs16[(size_t)(u6 & 0xFFFF) * 64 + lane];
        unsigned short m7 = xs16[(size_t)(u7 & 0xFFFF) * 64 + lane];
        float2 f0 = fp8x2_f32(m0);
        float2 f1 = fp8x2_f32(m1);
        float2 f2 = fp8x2_f32(m2);
        float2 f3 = fp8x2_f32(m3);
        float2 f4 = fp8x2_f32(m4);
        float2 f5 = fp8x2_f32(m5);
        float2 f6 = fp8x2_f32(m6);
        float2 f7 = fp8x2_f32(m7);
        float v0 = hu2f((unsigned short)(u0 >> 16));
        float v1 = hu2f((unsigned short)(u1 >> 16));
        float v2 = hu2f((unsigned short)(u2 >> 16));
        float v3 = hu2f((unsigned short)(u3 >> 16));
        float v4 = hu2f((unsigned short)(u4 >> 16));
        float v5 = hu2f((unsigned short)(u5 >> 16));
        float v6 = hu2f((unsigned short)(u6 >> 16));
        float v7 = hu2f((unsigned short)(u7 >> 16));
        accx += v0*f0.x + v1*f1.x + v2*f2.x + v3*f3.x
              + v4*f4.x + v5*f5.x + v6*f6.x + v7*f7.x;
        accy += v0*f0.y + v1*f1.y + v2*f2.y + v3*f3.y
              + v4*f4.y + v5*f5.y + v6*f6.y + v7*f7.y;
    }
    for (; i < n; i++) {
        unsigned u0 = (unsigned)__shfl(eh, i);
        float v0 = hu2f((unsigned short)(u0 >> 16));
        float2 f0 = fp8x2_f32(xs16[(size_t)(u0 & 0xFFFF) * 64 + lane]);
        accx += v0 * f0.x;
        accy += v0 * f0.y;
    }

    float2 b = ((const float2*)bias)[lane];
    float hx = fmaxf(dv * accx + b.x, 0.0f);
    float hy = fmaxf(dv * accy + b.y, 0.0f);
    float2 w = ((const float2*)Wh)[lane];
    float s = hx * w.x + hy * w.y;
#pragma unroll
    for (int off = 32; off > 0; off >>= 1) s += __shfl_down(s, off, 64);
    if (lane == 0) nodedot[node] = s;
}

// ---------------------------------------------------------------------------
// out[g] = (sum nodedot over graph)/cnt + bh; bounds via binary search.
// ---------------------------------------------------------------------------
__global__ __launch_bounds__(256) void final2_kernel(const float* __restrict__ nodedot,
                                                     const int* __restrict__ batch,
                                                     const float* __restrict__ bh,
                                                     float* __restrict__ out) {
    __shared__ float red[256];
    int g = blockIdx.x;
    int lo = 0, hi = N_NODES;
    while (lo < hi) { int mid = (lo + hi) >> 1; if (batch[mid] < g) lo = mid + 1; else hi = mid; }
    int a = lo;
    hi = N_NODES;
    while (lo < hi) { int mid = (lo + hi) >> 1; if (batch[mid] < g + 1) lo = mid + 1; else hi = mid; }
    int b = lo;

    float s = 0.0f;
    for (int n = a + threadIdx.x; n < b; n += 256) s += nodedot[n];
    red[threadIdx.x] = s;
    __syncthreads();
#pragma unroll
    for (int off = 128; off > 0; off >>= 1) {
        if (threadIdx.x < off) red[threadIdx.x] += red[threadIdx.x + off];
        __syncthreads();
    }
    if (threadIdx.x == 0)
        out[g] = red[0] / fmaxf((float)(b - a), 1.0f) + bh[0];
}

// ---------------------------------------------------------------------------
extern "C" void kernel_launch(void* const* d_in, const int* in_sizes, int n_in,
                              void* d_out, int out_size, void* d_ws, size_t ws_size,
                              hipStream_t stream) {
    const float* x   = (const float*)d_in[0];
    const float* ew  = (const float*)d_in[1];
    const float* W1  = (const float*)d_in[2];
    const float* b1  = (const float*)d_in[3];
    const float* W2  = (const float*)d_in[4];
    const float* b2  = (const float*)d_in[5];
    const float* Wh  = (const float*)d_in[6];
    const float* bh  = (const float*)d_in[7];
    const int*   ei  = (const int*)d_in[8];
    const int*   bat = (const int*)d_in[9];
    float* out = (float*)d_out;

    char* ws = (char*)d_ws;
    unsigned char* bufA8 = (unsigned char*)ws;            ws += (size_t)N_NODES * D;
    unsigned char* bufB8 = (unsigned char*)ws;            ws += (size_t)N_NODES * D;
    ws += 128 - ((size_t)ws & 127);                       // realign
    unsigned int* bucket = (unsigned int*)ws;             ws += (size_t)N_NODES * CAP * 4;
    unsigned long long* packed = (unsigned long long*)ws; ws += (size_t)N_NODES * 8;
    float*  nodedot = (float*)ws;                         ws += (size_t)N_NODES * 4;

    const int nb_agg4 = N_NODES / 4;                  // 12500

    hipMemsetAsync(packed, 0, (size_t)N_NODES * 8, stream);

    // gemm1 (x@W1 -> fp8, BK=32 LDS) overlapped with fill (atomic-floor-bound)
    fused_gemm1_fill<<<NB_GEMM1 + NB_FILL, 256, 0, stream>>>(x, W1, bufA8, ei, ew, packed, bucket);

    // layer 1 agg (fp8 gather, 2 lines/edge) + row-local gemm2 -> x2' (fp8)
    agg1_gemm2_kernel<<<NB_AGG16, 512, 0, stream>>>(bufA8, packed, bucket, b1, W2, bufB8);

    // layer 2 agg (fp8 gather) + head dot
    agg_head_kernel<<<nb_agg4, 256, 0, stream>>>(bufB8, packed, bucket, b2, Wh, nodedot);

    // segment-sum + head bias
    final2_kernel<<<N_GRAPHS, 256, 0, stream>>>(nodedot, bat, bh, out);
}

// Round 20
// 202.153 us; speedup vs baseline: 1.1342x; 1.0730x over previous
//
#include <hip/hip_runtime.h>
#include <hip/hip_bf16.h>
#include <hip/hip_fp16.h>
#include <hip/hip_fp8.h>

#define N_NODES  50000
#define N_EDGES  800000
#define D        128
#define N_GRAPHS 64
#define CAP      64          // bucket capacity; in-deg ~ Poisson(16), P(>=64) ~ 1e-19
#define EW_SCALE 1048576.0f  // 2^20 fixed-point for packed weighted-degree
#define NB_GEMM1 391         // ceil(50000/128)
#define NB_FILL  3125        // 800000/256
#define NB_AGG16 3125        // N_NODES/16

typedef _Float16 half8 __attribute__((ext_vector_type(8)));
typedef float   float4v __attribute__((ext_vector_type(4)));
typedef float   f32x2   __attribute__((ext_vector_type(2)));

__device__ __forceinline__ float2 h2f(unsigned int u) {
    __half2 h = *reinterpret_cast<__half2*>(&u);
    return __half22float2(h);
}
__device__ __forceinline__ float hu2f(unsigned short u) {
    __half_raw hr; hr.x = u;
    return __half2float(__half(hr));
}
// 2x fp8 e4m3 -> 2x f32 (v_cvt_pk_f32_fp8)
__device__ __forceinline__ float2 fp8x2_f32(unsigned short u) {
    f32x2 v = __builtin_amdgcn_cvt_pk_f32_fp8((int)u, false);
    return make_float2(v[0], v[1]);
}
__device__ __forceinline__ unsigned char f32_fp8(float f) {
    __hip_fp8_e4m3 q(f);
    return (unsigned char)q.__x;
}
// unpack packed word -> (cnt, dinv)
__device__ __forceinline__ void unpack_pd(unsigned long long p, int& n, float& dv) {
    int c = (int)(p >> 40);
    n = c < CAP ? c : CAP;
    dv = rsqrtf(1.0f + (float)(p & 0xFFFFFFFFFFULL) * (1.0f / EW_SCALE));
}

// ---------------------------------------------------------------------------
// FUSED: blocks [0,391) = gemm1 (fp32 x @ W1 -> FP8 e4m3, BK=32, LDS=32KB);
// blocks [391,3516) = fill (1 edge/thread, returning 64-bit atomic on 50K
// spread counters — chip-wide ~15G atomics/s floor). Bucket: src:u16|ew:fp16.
// ---------------------------------------------------------------------------
__global__ __launch_bounds__(256) void fused_gemm1_fill(const float* __restrict__ X,
                                                        const float* __restrict__ W,
                                                        unsigned char* __restrict__ Y8,
                                                        const int* __restrict__ ei,
                                                        const float* __restrict__ ew,
                                                        unsigned long long* __restrict__ packed,
                                                        unsigned int* __restrict__ bucket) {
    __shared__ float XT[32 * 128];  // 16 KB
    __shared__ float Ws[32 * 128];  // 16 KB

    if (blockIdx.x >= NB_GEMM1) {
        int e = (blockIdx.x - NB_GEMM1) * 256 + threadIdx.x;
        if (e >= N_EDGES) return;
        int r = ei[e];
        int c = ei[N_EDGES + e];
        float w = ew[e];
        unsigned long long add = (1ULL << 40) | (unsigned long long)(unsigned)(w * EW_SCALE + 0.5f);
        unsigned long long old = atomicAdd(&packed[c], add);
        unsigned pos = (unsigned)(old >> 40);
        if (pos < CAP) {
            unsigned short wh = __half_as_ushort(__float2half_rn(w));
            bucket[(size_t)c * CAP + pos] = (unsigned)r | ((unsigned)wh << 16);
        }
        return;
    }

    const int tid  = threadIdx.x;
    const int row0 = blockIdx.x * 128;
    const int tr = tid >> 4, tc = tid & 15;
    float acc[8][8] = {};

    for (int kt = 0; kt < 4; kt++) {
        const int kbase = kt * 32;
        {
            const float4* src = (const float4*)(W + kbase * 128);
            float4* dst = (float4*)Ws;
            for (int i = tid; i < 1024; i += 256) dst[i] = src[i];
        }
        {
            int r  = tid >> 1;
            int rr = row0 + r; if (rr >= N_NODES) rr = N_NODES - 1;
            int k0 = (tid & 1) * 16;
            const float4* src = (const float4*)(X + (size_t)rr * 128 + kbase + k0);
#pragma unroll
            for (int i = 0; i < 4; i++) {
                float4 v = src[i];
                int k = k0 + i * 4;
                XT[(k + 0) * 128 + r] = v.x;
                XT[(k + 1) * 128 + r] = v.y;
                XT[(k + 2) * 128 + r] = v.z;
                XT[(k + 3) * 128 + r] = v.w;
            }
        }
        __syncthreads();
#pragma unroll 4
        for (int k = 0; k < 32; k++) {
            float xs[8], ws[8];
            *(float4*)&xs[0] = *(const float4*)(XT + k * 128 + tr * 8);
            *(float4*)&xs[4] = *(const float4*)(XT + k * 128 + tr * 8 + 4);
            *(float4*)&ws[0] = *(const float4*)(Ws + k * 128 + tc * 8);
            *(float4*)&ws[4] = *(const float4*)(Ws + k * 128 + tc * 8 + 4);
#pragma unroll
            for (int i = 0; i < 8; i++)
#pragma unroll
                for (int j = 0; j < 8; j++)
                    acc[i][j] += xs[i] * ws[j];
        }
        __syncthreads();
    }
#pragma unroll
    for (int i = 0; i < 8; i++) {
        int r = row0 + tr * 8 + i;
        if (r < N_NODES) {
            uint2 p;
            p.x = (unsigned)f32_fp8(acc[i][0]) | ((unsigned)f32_fp8(acc[i][1]) << 8)
                | ((unsigned)f32_fp8(acc[i][2]) << 16) | ((unsigned)f32_fp8(acc[i][3]) << 24);
            p.y = (unsigned)f32_fp8(acc[i][4]) | ((unsigned)f32_fp8(acc[i][5]) << 8)
                | ((unsigned)f32_fp8(acc[i][6]) << 16) | ((unsigned)f32_fp8(acc[i][7]) << 24);
            *(uint2*)(Y8 + (size_t)r * 128 + tc * 8) = p;
        }
    }
}

// ---------------------------------------------------------------------------
// Layer-1 agg + row-local gemm2. 512 threads = 8 waves; 16 nodes/block.
// Each wave INTERLEAVES its 2 nodes: headers issued back-to-back, gather loop
// does 4 gathers/node/chunk = 8 independent loads in flight (2x MLP vs r19).
// Zero-pad trick: pk=0 beyond n -> val 0, harmless row-0 gather; one loop to
// max(nA,nB). h1 staged fp16 in LDS; MFMA col-tile wv; x2' written FP8.
// ---------------------------------------------------------------------------
__global__ __launch_bounds__(512) void agg1_gemm2_kernel(const unsigned char* __restrict__ x8in,
                                                         const unsigned long long* __restrict__ packed,
                                                         const unsigned int* __restrict__ bucket,
                                                         const float* __restrict__ b1,
                                                         const float* __restrict__ W2,
                                                         unsigned char* __restrict__ x2) {
    __shared__ _Float16 sh1[16][136];
    const int wv   = threadIdx.x >> 6;     // 0..7
    const int lane = threadIdx.x & 63;
    const unsigned short* xs16 = (const unsigned short*)x8in;  // 2 fp8 per ushort
    const int node0 = blockIdx.x * 16;

    float2 bb = ((const float2*)b1)[lane];

    const int nodeA = node0 + wv * 2;
    const int nodeB = nodeA + 1;
    int nA; float dvA; unpack_pd(packed[nodeA], nA, dvA);
    int nB; float dvB; unpack_pd(packed[nodeB], nB, dvB);

    unsigned pkA = 0u, pkB = 0u;
    if (lane < nA) {
        unsigned eh = bucket[(size_t)nodeA * CAP + lane];
        int src = eh & 0xFFFFu;
        int sn; float sdv; unpack_pd(packed[src], sn, sdv);
        float v = hu2f((unsigned short)(eh >> 16)) * sdv;
        pkA = (unsigned)src | ((unsigned)__half_as_ushort(__float2half_rn(v)) << 16);
    }
    if (lane < nB) {
        unsigned eh = bucket[(size_t)nodeB * CAP + lane];
        int src = eh & 0xFFFFu;
        int sn; float sdv; unpack_pd(packed[src], sn, sdv);
        float v = hu2f((unsigned short)(eh >> 16)) * sdv;
        pkB = (unsigned)src | ((unsigned)__half_as_ushort(__float2half_rn(v)) << 16);
    }
    int pkiA = (int)pkA, pkiB = (int)pkB;

    float2 xsA = fp8x2_f32(xs16[(size_t)nodeA * 64 + lane]);
    float2 xsB = fp8x2_f32(xs16[(size_t)nodeB * 64 + lane]);
    float aAx = dvA * xsA.x, aAy = dvA * xsA.y;
    float aBx = dvB * xsB.x, aBy = dvB * xsB.y;

    int nmax = nA > nB ? nA : nB;
    for (int i = 0; i < nmax; i += 4) {
        unsigned a0 = (unsigned)__shfl(pkiA, i);
        unsigned a1 = (unsigned)__shfl(pkiA, i + 1);
        unsigned a2 = (unsigned)__shfl(pkiA, i + 2);
        unsigned a3 = (unsigned)__shfl(pkiA, i + 3);
        unsigned b0 = (unsigned)__shfl(pkiB, i);
        unsigned b1u = (unsigned)__shfl(pkiB, i + 1);
        unsigned b2 = (unsigned)__shfl(pkiB, i + 2);
        unsigned b3 = (unsigned)__shfl(pkiB, i + 3);
        unsigned short mA0 = xs16[(size_t)(a0 & 0xFFFF) * 64 + lane];
        unsigned short mA1 = xs16[(size_t)(a1 & 0xFFFF) * 64 + lane];
        unsigned short mA2 = xs16[(size_t)(a2 & 0xFFFF) * 64 + lane];
        unsigned short mA3 = xs16[(size_t)(a3 & 0xFFFF) * 64 + lane];
        unsigned short mB0 = xs16[(size_t)(b0 & 0xFFFF) * 64 + lane];
        unsigned short mB1 = xs16[(size_t)(b1u & 0xFFFF) * 64 + lane];
        unsigned short mB2 = xs16[(size_t)(b2 & 0xFFFF) * 64 + lane];
        unsigned short mB3 = xs16[(size_t)(b3 & 0xFFFF) * 64 + lane];
        float2 fA0 = fp8x2_f32(mA0), fA1 = fp8x2_f32(mA1);
        float2 fA2 = fp8x2_f32(mA2), fA3 = fp8x2_f32(mA3);
        float2 fB0 = fp8x2_f32(mB0), fB1 = fp8x2_f32(mB1);
        float2 fB2 = fp8x2_f32(mB2), fB3 = fp8x2_f32(mB3);
        float vA0 = hu2f((unsigned short)(a0 >> 16));
        float vA1 = hu2f((unsigned short)(a1 >> 16));
        float vA2 = hu2f((unsigned short)(a2 >> 16));
        float vA3 = hu2f((unsigned short)(a3 >> 16));
        float vB0 = hu2f((unsigned short)(b0 >> 16));
        float vB1 = hu2f((unsigned short)(b1u >> 16));
        float vB2 = hu2f((unsigned short)(b2 >> 16));
        float vB3 = hu2f((unsigned short)(b3 >> 16));
        aAx += vA0*fA0.x + vA1*fA1.x + vA2*fA2.x + vA3*fA3.x;
        aAy += vA0*fA0.y + vA1*fA1.y + vA2*fA2.y + vA3*fA3.y;
        aBx += vB0*fB0.x + vB1*fB1.x + vB2*fB2.x + vB3*fB3.x;
        aBy += vB0*fB0.y + vB1*fB1.y + vB2*fB2.y + vB3*fB3.y;
    }

    float hAx = fmaxf(dvA * aAx + bb.x, 0.0f);
    float hAy = fmaxf(dvA * aAy + bb.y, 0.0f);
    float hBx = fmaxf(dvB * aBx + bb.x, 0.0f);
    float hBy = fmaxf(dvB * aBy + bb.y, 0.0f);
    sh1[wv * 2][lane * 2]         = (_Float16)hAx;
    sh1[wv * 2][lane * 2 + 1]     = (_Float16)hAy;
    sh1[wv * 2 + 1][lane * 2]     = (_Float16)hBx;
    sh1[wv * 2 + 1][lane * 2 + 1] = (_Float16)hBy;
    __syncthreads();

    // --- MFMA: rows node0..node0+15; wave wv computes col-tile wv (16 cols).
    const int quad = lane >> 4;
    const int l16  = lane & 15;
    float4v acc0 = {};
#pragma unroll
    for (int kc = 0; kc < 4; kc++) {
        const int k0 = kc * 32;
        half8 a = *(const half8*)(&sh1[l16][k0 + quad * 8]);
        const float* wp = W2 + (size_t)(k0 + quad * 8) * 128 + wv * 16 + l16;
        half8 b;
#pragma unroll
        for (int jj = 0; jj < 8; jj++) b[jj] = (_Float16)wp[jj * 128];
        acc0 = __builtin_amdgcn_mfma_f32_16x16x32_f16(a, b, acc0, 0, 0, 0);
    }
#pragma unroll
    for (int r = 0; r < 4; r++) {
        int row = node0 + quad * 4 + r;
        int rn; float s;
        unpack_pd(packed[row], rn, s);
        x2[(size_t)row * 128 + wv * 16 + l16] = f32_fp8(acc0[r] * s);
    }
}

// ---------------------------------------------------------------------------
// Layer-2 agg + head dot, 2-node interleaved per wave (8 nodes/block,
// 6250 blocks). 8 independent gathers in flight per chunk.
// ---------------------------------------------------------------------------
__global__ __launch_bounds__(256) void agg_head_kernel(const unsigned char* __restrict__ x8,
                                                       const unsigned long long* __restrict__ packed,
                                                       const unsigned int* __restrict__ bucket,
                                                       const float* __restrict__ bias,
                                                       const float* __restrict__ Wh,
                                                       float* __restrict__ nodedot) {
    const int wv   = threadIdx.x >> 6;
    const int lane = threadIdx.x & 63;
    const unsigned short* xs16 = (const unsigned short*)x8;

    const int nodeA = blockIdx.x * 8 + wv * 2;
    const int nodeB = nodeA + 1;
    int nA; float dvA; unpack_pd(packed[nodeA], nA, dvA);
    int nB; float dvB; unpack_pd(packed[nodeB], nB, dvB);

    unsigned ehA = (lane < nA) ? bucket[(size_t)nodeA * CAP + lane] : 0u;
    unsigned ehB = (lane < nB) ? bucket[(size_t)nodeB * CAP + lane] : 0u;
    int eiA = (int)ehA, eiB = (int)ehB;

    float2 xsA = fp8x2_f32(xs16[(size_t)nodeA * 64 + lane]);
    float2 xsB = fp8x2_f32(xs16[(size_t)nodeB * 64 + lane]);
    float aAx = xsA.x, aAy = xsA.y;
    float aBx = xsB.x, aBy = xsB.y;

    int nmax = nA > nB ? nA : nB;
    for (int i = 0; i < nmax; i += 4) {
        unsigned a0 = (unsigned)__shfl(eiA, i);
        unsigned a1 = (unsigned)__shfl(eiA, i + 1);
        unsigned a2 = (unsigned)__shfl(eiA, i + 2);
        unsigned a3 = (unsigned)__shfl(eiA, i + 3);
        unsigned b0 = (unsigned)__shfl(eiB, i);
        unsigned b1u = (unsigned)__shfl(eiB, i + 1);
        unsigned b2 = (unsigned)__shfl(eiB, i + 2);
        unsigned b3 = (unsigned)__shfl(eiB, i + 3);
        unsigned short mA0 = xs16[(size_t)(a0 & 0xFFFF) * 64 + lane];
        unsigned short mA1 = xs16[(size_t)(a1 & 0xFFFF) * 64 + lane];
        unsigned short mA2 = xs16[(size_t)(a2 & 0xFFFF) * 64 + lane];
        unsigned short mA3 = xs16[(size_t)(a3 & 0xFFFF) * 64 + lane];
        unsigned short mB0 = xs16[(size_t)(b0 & 0xFFFF) * 64 + lane];
        unsigned short mB1 = xs16[(size_t)(b1u & 0xFFFF) * 64 + lane];
        unsigned short mB2 = xs16[(size_t)(b2 & 0xFFFF) * 64 + lane];
        unsigned short mB3 = xs16[(size_t)(b3 & 0xFFFF) * 64 + lane];
        float2 fA0 = fp8x2_f32(mA0), fA1 = fp8x2_f32(mA1);
        float2 fA2 = fp8x2_f32(mA2), fA3 = fp8x2_f32(mA3);
        float2 fB0 = fp8x2_f32(mB0), fB1 = fp8x2_f32(mB1);
        float2 fB2 = fp8x2_f32(mB2), fB3 = fp8x2_f32(mB3);
        float vA0 = hu2f((unsigned short)(a0 >> 16));
        float vA1 = hu2f((unsigned short)(a1 >> 16));
        float vA2 = hu2f((unsigned short)(a2 >> 16));
        float vA3 = hu2f((unsigned short)(a3 >> 16));
        float vB0 = hu2f((unsigned short)(b0 >> 16));
        float vB1 = hu2f((unsigned short)(b1u >> 16));
        float vB2 = hu2f((unsigned short)(b2 >> 16));
        float vB3 = hu2f((unsigned short)(b3 >> 16));
        aAx += vA0*fA0.x + vA1*fA1.x + vA2*fA2.x + vA3*fA3.x;
        aAy += vA0*fA0.y + vA1*fA1.y + vA2*fA2.y + vA3*fA3.y;
        aBx += vB0*fB0.x + vB1*fB1.x + vB2*fB2.x + vB3*fB3.x;
        aBy += vB0*fB0.y + vB1*fB1.y + vB2*fB2.y + vB3*fB3.y;
    }

    float2 b = ((const float2*)bias)[lane];
    float2 w = ((const float2*)Wh)[lane];
    float hAx = fmaxf(dvA * aAx + b.x, 0.0f);
    float hAy = fmaxf(dvA * aAy + b.y, 0.0f);
    float hBx = fmaxf(dvB * aBx + b.x, 0.0f);
    float hBy = fmaxf(dvB * aBy + b.y, 0.0f);
    float sA = hAx * w.x + hAy * w.y;
    float sB = hBx * w.x + hBy * w.y;
#pragma unroll
    for (int off = 32; off > 0; off >>= 1) {
        sA += __shfl_down(sA, off, 64);
        sB += __shfl_down(sB, off, 64);
    }
    if (lane == 0) {
        nodedot[nodeA] = sA;
        nodedot[nodeB] = sB;
    }
}

// ---------------------------------------------------------------------------
// out[g] = (sum nodedot over graph)/cnt + bh; bounds via binary search.
// ---------------------------------------------------------------------------
__global__ __launch_bounds__(256) void final2_kernel(const float* __restrict__ nodedot,
                                                     const int* __restrict__ batch,
                                                     const float* __restrict__ bh,
                                                     float* __restrict__ out) {
    __shared__ float red[256];
    int g = blockIdx.x;
    int lo = 0, hi = N_NODES;
    while (lo < hi) { int mid = (lo + hi) >> 1; if (batch[mid] < g) lo = mid + 1; else hi = mid; }
    int a = lo;
    hi = N_NODES;
    while (lo < hi) { int mid = (lo + hi) >> 1; if (batch[mid] < g + 1) lo = mid + 1; else hi = mid; }
    int b = lo;

    float s = 0.0f;
    for (int n = a + threadIdx.x; n < b; n += 256) s += nodedot[n];
    red[threadIdx.x] = s;
    __syncthreads();
#pragma unroll
    for (int off = 128; off > 0; off >>= 1) {
        if (threadIdx.x < off) red[threadIdx.x] += red[threadIdx.x + off];
        __syncthreads();
    }
    if (threadIdx.x == 0)
        out[g] = red[0] / fmaxf((float)(b - a), 1.0f) + bh[0];
}

// ---------------------------------------------------------------------------
extern "C" void kernel_launch(void* const* d_in, const int* in_sizes, int n_in,
                              void* d_out, int out_size, void* d_ws, size_t ws_size,
                              hipStream_t stream) {
    const float* x   = (const float*)d_in[0];
    const float* ew  = (const float*)d_in[1];
    const float* W1  = (const float*)d_in[2];
    const float* b1  = (const float*)d_in[3];
    const float* W2  = (const float*)d_in[4];
    const float* b2  = (const float*)d_in[5];
    const float* Wh  = (const float*)d_in[6];
    const float* bh  = (const float*)d_in[7];
    const int*   ei  = (const int*)d_in[8];
    const int*   bat = (const int*)d_in[9];
    float* out = (float*)d_out;

    char* ws = (char*)d_ws;
    unsigned char* bufA8 = (unsigned char*)ws;            ws += (size_t)N_NODES * D;
    unsigned char* bufB8 = (unsigned char*)ws;            ws += (size_t)N_NODES * D;
    ws += 128 - ((size_t)ws & 127);                       // realign
    unsigned int* bucket = (unsigned int*)ws;             ws += (size_t)N_NODES * CAP * 4;
    unsigned long long* packed = (unsigned long long*)ws; ws += (size_t)N_NODES * 8;
    float*  nodedot = (float*)ws;                         ws += (size_t)N_NODES * 4;

    const int nb_agg8 = N_NODES / 8;                  // 6250

    hipMemsetAsync(packed, 0, (size_t)N_NODES * 8, stream);

    // gemm1 (x@W1 -> fp8, BK=32 LDS) overlapped with fill (atomic-floor-bound)
    fused_gemm1_fill<<<NB_GEMM1 + NB_FILL, 256, 0, stream>>>(x, W1, bufA8, ei, ew, packed, bucket);

    // layer 1 agg (2-node interleave, 8 gathers in flight) + gemm2 -> x2' fp8
    agg1_gemm2_kernel<<<NB_AGG16, 512, 0, stream>>>(bufA8, packed, bucket, b1, W2, bufB8);

    // layer 2 agg (2-node interleave) + head dot
    agg_head_kernel<<<nb_agg8, 256, 0, stream>>>(bufB8, packed, bucket, b2, Wh, nodedot);

    // segment-sum + head bias
    final2_kernel<<<N_GRAPHS, 256, 0, stream>>>(nodedot, bat, bh, out);
}